// Round 4
// baseline (132.539 us; speedup 1.0000x reference)
//
#include <hip/hip_runtime.h>
#include <hip/hip_fp16.h>
#include <math.h>

#define NA_ 10000
#define NM_ 150000
#define B_  4
#define NS_ 4
#define NMAX_ 32
#define NO_ 4
#define H1_ 4
#define H2_ 38
#define PPT_ 8
#define PI_F 3.14159265358979323846f

// ---- ws layout (main path) ----
#define CSN_OFF   ((size_t)0)
#define CSN_BYTES ((size_t)B_ * NA_ * NMAX_ * 4)     // 5,120,000
#define R_OFF     (CSN_OFF + CSN_BYTES)
#define R_BYTES   ((size_t)B_ * NM_ * NMAX_ * 2)     // 38,400,000
#define ST_OFF    (R_OFF + R_BYTES)
#define ST_BYTES  ((size_t)B_ * (NA_ + 1) * 4 + 16)
#define WS_NEED   (ST_OFF + ST_BYTES)

// ---------------------------------------------------------------------------
// Kernel 0: segment starts from sorted iidx.
// ---------------------------------------------------------------------------
__global__ void starts_kernel(const int* __restrict__ iidx, int* __restrict__ starts) {
    int p = blockIdx.x * blockDim.x + threadIdx.x;
    if (p >= B_ * NM_) return;
    int b = p / NM_, pl = p - b * NM_;
    const int* ii = iidx + (size_t)b * NM_;
    int* st = starts + (size_t)b * (NA_ + 1);
    int cur = ii[pl];
    int prev = (pl == 0) ? -1 : ii[pl - 1];
    for (int a = prev + 1; a <= cur; ++a) st[a] = pl;
    if (pl == NM_ - 1) {
        for (int a = cur + 1; a <= NA_; ++a) st[a] = NM_;
    }
}

// ---------------------------------------------------------------------------
// prep0: R[b][p][n] = fcut * exp(alpha[jat][n] * (dist - rs[jat][n])^2), fp16.
// Half-wave (32 lanes, lane=n) processes PPT_ consecutive pairs; tables in
// registers; 8 independent chains per thread for ILP.
// ---------------------------------------------------------------------------
__global__ __launch_bounds__(256) void prep0_kernel(
    const float* __restrict__ disp, const float* __restrict__ alpha,
    const float* __restrict__ rsp, const int* __restrict__ jidx,
    const int* __restrict__ sorted_numbers, __half* __restrict__ R)
{
    int wid = (blockIdx.x * 256 + threadIdx.x) >> 6;
    int lane = threadIdx.x & 63;
    int h = lane >> 5, n = lane & 31;
    int ghalf = wid * 2 + h;                 // [0, B*NM/PPT)
    constexpr int HPI = NM_ / PPT_;          // halves per image
    int b = ghalf / HPI;
    int pbase = (ghalf - b * HPI) * PPT_;

    float al0 = alpha[n],      al1 = alpha[32 + n];
    float al2 = alpha[64 + n], al3 = alpha[96 + n];
    float rv0 = rsp[n],        rv1 = rsp[32 + n];
    float rv2 = rsp[64 + n],   rv3 = rsp[96 + n];

    const int* jjb = jidx + (size_t)b * NM_;
    const float* dpb = disp + (size_t)b * NM_ * 3;
    __half* Rb = R + (size_t)b * NM_ * NMAX_;

#pragma unroll
    for (int k = 0; k < PPT_; ++k) {
        int p = pbase + k;
        int j = jjb[p];
        float x = dpb[p * 3 + 0];
        float y = dpb[p * 3 + 1];
        float z = dpb[p * 3 + 2];
        int jat = sorted_numbers[j];
        float dist = sqrtf(x * x + y * y + z * z);
        float c = __cosf(dist * (PI_F / 6.0f));
        float fc = 0.25f * (c + 1.f) * (c + 1.f);
        bool s0 = (jat & 1) != 0, s1 = (jat & 2) != 0;
        float av = s1 ? (s0 ? al3 : al2) : (s0 ? al1 : al0);
        float rv = s1 ? (s0 ? rv3 : rv2) : (s0 ? rv1 : rv0);
        float dd = dist - rv;
        Rb[(size_t)p * NMAX_ + n] = __float2half(fc * __expf(av * dd * dd));
    }
}

// ---------------------------------------------------------------------------
// prep1: in-place fold R[p][n] *= csn2[j[p]][n]. Fully pair-parallel,
// latency-tolerant. Safe across graph replays: prep0 rewrites all of R.
// ---------------------------------------------------------------------------
__global__ __launch_bounds__(256) void prep1_kernel(
    const int* __restrict__ jidx, const float* __restrict__ csn2,
    __half* __restrict__ R)
{
    int wid = (blockIdx.x * 256 + threadIdx.x) >> 6;
    int lane = threadIdx.x & 63;
    int h = lane >> 5, n = lane & 31;
    int ghalf = wid * 2 + h;
    constexpr int HPI = NM_ / PPT_;
    int b = ghalf / HPI;
    int pbase = (ghalf - b * HPI) * PPT_;

    const int* jjb = jidx + (size_t)b * NM_;
    const float* csb = csn2 + (size_t)b * NA_ * NMAX_;
    __half* Rb = R + (size_t)b * NM_ * NMAX_;

#pragma unroll
    for (int k = 0; k < PPT_; ++k) {
        int p = pbase + k;
        int j = jjb[p];
        float r = __half2float(Rb[(size_t)p * NMAX_ + n]);
        float cv = csb[(size_t)j * NMAX_ + n];
        Rb[(size_t)p * NMAX_ + n] = __float2half(r * cv);
    }
}

// ---------------------------------------------------------------------------
// pass: one wave = TWO atoms (32-lane halves, lane=n). Streaming walk over the
// atom's contiguous pair range.
// PASS=0: coef = R * spv[sn[j]] (j @ dist 3, sn @ dist 2); epilogue MLP->csn2.
// PASS=1: coef = R (csn2 pre-folded); zero indirection; epilogue rho->out.
// ---------------------------------------------------------------------------
template <int PASS>
__global__ __launch_bounds__(256) void pass_kernel(
    const __half* __restrict__ R, const float* __restrict__ disp,
    const int* __restrict__ jidx, const float* __restrict__ spp,
    const float* __restrict__ op, const float* __restrict__ w1,
    const float* __restrict__ b1, const float* __restrict__ w2,
    const float* __restrict__ b2, const float* __restrict__ w3,
    const float* __restrict__ b3, const int* __restrict__ sorted_numbers,
    const int* __restrict__ starts, float* __restrict__ csn2,
    float* __restrict__ out)
{
    int wave = blockIdx.x * 4 + (threadIdx.x >> 6);
    int lane = threadIdx.x & 63;
    int h = lane >> 5, n = lane & 31;
    int g = wave * 2 + h;                 // b*NA + a
    if (g >= B_ * NA_) return;
    int b = g / NA_, a = g - b * NA_;

    float spv[NS_];
    if constexpr (PASS == 0) {
#pragma unroll
        for (int s = 0; s < NS_; ++s) spv[s] = spp[s * NMAX_ + n];
    }

    const float* opb = op + (size_t)PASS * 2 * NMAX_ * NO_;
    float W0[NO_], W1[NO_];
#pragma unroll
    for (int o = 0; o < NO_; ++o) {
        W0[o] = opb[(0 * NMAX_ + n) * NO_ + o];
        W1[o] = opb[(1 * NMAX_ + n) * NO_ + o];
    }

    const int* st = starts + b * (NA_ + 1);
    int p0 = st[a], p1 = st[a + 1];
    const __half* Rb = R + (size_t)b * NM_ * NMAX_;
    const float* dpb = disp + (size_t)b * NM_ * 3;
    const int* jjb = jidx + (size_t)b * NM_;

    float acc0 = 0.f, acc1 = 0.f, acc2 = 0.f, acc3 = 0.f;

    if (p0 < p1) {
        int last = p1 - 1;
        int pB = (p0 + 1 < last) ? p0 + 1 : last;
        int pC = (p0 + 2 < last) ? p0 + 2 : last;
        // stage A (pair p), stage B (pair p+1) resident; j2 = j of pair p+2
        float xA = dpb[p0 * 3 + 0], yA = dpb[p0 * 3 + 1], zA = dpb[p0 * 3 + 2];
        float RA = __half2float(Rb[(size_t)p0 * NMAX_ + n]);
        float xB = dpb[pB * 3 + 0], yB = dpb[pB * 3 + 1], zB = dpb[pB * 3 + 2];
        float RB = __half2float(Rb[(size_t)pB * NMAX_ + n]);
        int jatA = 0, jatB = 0, j2 = 0;
        if constexpr (PASS == 0) {
            jatA = sorted_numbers[jjb[p0]];
            jatB = sorted_numbers[jjb[pB]];
            j2 = jjb[pC];
        }

        for (int p = p0; p <= last; ++p) {
            int p2 = (p + 2 < last) ? p + 2 : last;
            // incoming stage (pair p+2): xyz + R at distance 2
            float xN = dpb[p2 * 3 + 0];
            float yN = dpb[p2 * 3 + 1];
            float zN = dpb[p2 * 3 + 2];
            float RN = __half2float(Rb[(size_t)p2 * NMAX_ + n]);
            int jatN = 0, jN = 0;
            if constexpr (PASS == 0) {
                int p3 = (p + 3 < last) ? p + 3 : last;
                jatN = sorted_numbers[j2];   // sn gather at distance 2
                jN = jjb[p3];                // j load at distance 3
            }

            float coef;
            if constexpr (PASS == 0) {
                bool s0 = (jatA & 1) != 0, s1 = (jatA & 2) != 0;
                float cj = s1 ? (s0 ? spv[3] : spv[2]) : (s0 ? spv[1] : spv[0]);
                coef = RA * cj;
            } else {
                coef = RA;
            }
            acc0 += coef;
            acc1 = fmaf(coef, xA, acc1);
            acc2 = fmaf(coef, yA, acc2);
            acc3 = fmaf(coef, zA, acc3);

            xA = xB; yA = yB; zA = zB; RA = RB;
            xB = xN; yB = yN; zB = zN; RB = RN;
            if constexpr (PASS == 0) { jatA = jatB; jatB = jatN; j2 = jN; }
        }
    }

    // t[l][o] butterfly over the 32-lane half
    float t[4][NO_];
#pragma unroll
    for (int o = 0; o < NO_; ++o) {
        t[0][o] = W0[o] * acc0;
        t[1][o] = W1[o] * acc1;
        t[2][o] = W1[o] * acc2;
        t[3][o] = W1[o] * acc3;
    }
#pragma unroll
    for (int off = 1; off < 32; off <<= 1) {
#pragma unroll
        for (int l = 0; l < 4; ++l)
#pragma unroll
            for (int o = 0; o < NO_; ++o)
                t[l][o] += __shfl_xor(t[l][o], off);
    }
    float rho[NO_];
#pragma unroll
    for (int o = 0; o < NO_; ++o)
        rho[o] = t[0][o] * t[0][o] + t[1][o] * t[1][o] +
                 t[2][o] * t[2][o] + t[3][o] * t[3][o];

    if constexpr (PASS == 1) {
        if (n == 0) {
            *reinterpret_cast<float4*>(out + (size_t)g * NO_) =
                make_float4(rho[0], rho[1], rho[2], rho[3]);
        }
    } else {
        float h1v[H1_];
#pragma unroll
        for (int k = 0; k < H1_; ++k) {
            float s = b1[k];
#pragma unroll
            for (int o = 0; o < NO_; ++o) s = fmaf(rho[o], w1[o * H1_ + k], s);
            h1v[k] = tanhf(s);
        }
        float sa = b2[n];
        int jbi = 32 + (n < 6 ? n : 5);
        float sb = b2[jbi];
#pragma unroll
        for (int k = 0; k < H1_; ++k) {
            sa = fmaf(h1v[k], w2[k * H2_ + n], sa);
            sb = fmaf(h1v[k], w2[k * H2_ + jbi], sb);
        }
        float hva = tanhf(sa);
        float hvb = tanhf(sb);
        float on = b3[n];
        int base_lane = h << 5;
#pragma unroll
        for (int j2i = 0; j2i < 32; ++j2i) {
            float hj = __shfl(hva, base_lane + j2i);
            on = fmaf(hj, w3[j2i * NMAX_ + n], on);
        }
#pragma unroll
        for (int j2i = 0; j2i < 6; ++j2i) {
            float hj = __shfl(hvb, base_lane + j2i);
            on = fmaf(hj, w3[(32 + j2i) * NMAX_ + n], on);
        }
        int aat = sorted_numbers[a];
        bool t0b = (aat & 1) != 0, t1b = (aat & 2) != 0;
        float basev = t1b ? (t0b ? spv[3] : spv[2]) : (t0b ? spv[1] : spv[0]);
        csn2[(size_t)g * NMAX_ + n] = basev + on;
    }
}

// ---------------------------------------------------------------------------
// Fallback pass kernel (round-2 proven code) — used if ws_size too small.
// ---------------------------------------------------------------------------
template <int PASS>
__global__ __launch_bounds__(256) void fb_pass_kernel(
    const float* __restrict__ disp, const float* __restrict__ alpha,
    const float* __restrict__ rsp, const float* __restrict__ spp,
    const float* __restrict__ op, const float* __restrict__ w1,
    const float* __restrict__ b1, const float* __restrict__ w2,
    const float* __restrict__ b2, const float* __restrict__ w3,
    const float* __restrict__ b3, const int* __restrict__ jidx,
    const int* __restrict__ sorted_numbers, const int* __restrict__ starts,
    float* __restrict__ csn2, float* __restrict__ out)
{
    int wave = blockIdx.x * 4 + (threadIdx.x >> 6);
    int lane = threadIdx.x & 63;
    int h = lane >> 5;
    int n = lane & 31;
    int g = wave * 2 + h;
    if (g >= B_ * NA_) return;
    int b = g / NA_, a = g - b * NA_;

    float al[NS_], rv[NS_], spv[NS_];
#pragma unroll
    for (int s = 0; s < NS_; ++s) {
        al[s] = alpha[s * NMAX_ + n];
        rv[s] = rsp[s * NMAX_ + n];
        spv[s] = spp[s * NMAX_ + n];
    }
    const float* opb = op + (size_t)PASS * 2 * NMAX_ * NO_;
    float W0[NO_], W1[NO_];
#pragma unroll
    for (int o = 0; o < NO_; ++o) {
        W0[o] = opb[(0 * NMAX_ + n) * NO_ + o];
        W1[o] = opb[(1 * NMAX_ + n) * NO_ + o];
    }
    const int* st = starts + b * (NA_ + 1);
    int p0 = st[a], p1 = st[a + 1];
    const int* jjb = jidx + (size_t)b * NM_;
    const float* dpb = disp + (size_t)b * NM_ * 3;
    const float* csb = csn2 + (size_t)b * NA_ * NMAX_;

    float acc0 = 0.f, acc1 = 0.f, acc2 = 0.f, acc3 = 0.f;
    for (int p = p0; p < p1; ++p) {
        int j = jjb[p];
        float x = dpb[p * 3 + 0], y = dpb[p * 3 + 1], z = dpb[p * 3 + 2];
        float dist = sqrtf(x * x + y * y + z * z);
        float c = __cosf(dist * (PI_F / 6.0f));
        float fcv = 0.25f * (c + 1.f) * (c + 1.f);
        int jat = sorted_numbers[j];
        bool s0 = (jat & 1) != 0, s1 = (jat & 2) != 0;
        float av = s1 ? (s0 ? al[3] : al[2]) : (s0 ? al[1] : al[0]);
        float rsv = s1 ? (s0 ? rv[3] : rv[2]) : (s0 ? rv[1] : rv[0]);
        float cj;
        if constexpr (PASS == 0)
            cj = s1 ? (s0 ? spv[3] : spv[2]) : (s0 ? spv[1] : spv[0]);
        else
            cj = csb[(size_t)j * NMAX_ + n];
        float dd = dist - rsv;
        float coef = fcv * cj * __expf(av * dd * dd);
        acc0 += coef;
        acc1 = fmaf(coef, x, acc1);
        acc2 = fmaf(coef, y, acc2);
        acc3 = fmaf(coef, z, acc3);
    }
    float t[4][NO_];
#pragma unroll
    for (int o = 0; o < NO_; ++o) {
        t[0][o] = W0[o] * acc0; t[1][o] = W1[o] * acc1;
        t[2][o] = W1[o] * acc2; t[3][o] = W1[o] * acc3;
    }
#pragma unroll
    for (int off = 1; off < 32; off <<= 1) {
#pragma unroll
        for (int l = 0; l < 4; ++l)
#pragma unroll
            for (int o = 0; o < NO_; ++o)
                t[l][o] += __shfl_xor(t[l][o], off);
    }
    float rho[NO_];
#pragma unroll
    for (int o = 0; o < NO_; ++o)
        rho[o] = t[0][o] * t[0][o] + t[1][o] * t[1][o] +
                 t[2][o] * t[2][o] + t[3][o] * t[3][o];
    if constexpr (PASS == 1) {
        if (n == 0)
            *reinterpret_cast<float4*>(out + (size_t)g * NO_) =
                make_float4(rho[0], rho[1], rho[2], rho[3]);
    } else {
        float h1v[H1_];
#pragma unroll
        for (int k = 0; k < H1_; ++k) {
            float s = b1[k];
#pragma unroll
            for (int o = 0; o < NO_; ++o) s = fmaf(rho[o], w1[o * H1_ + k], s);
            h1v[k] = tanhf(s);
        }
        float sa = b2[n];
        int jbi = 32 + (n < 6 ? n : 5);
        float sb = b2[jbi];
#pragma unroll
        for (int k = 0; k < H1_; ++k) {
            sa = fmaf(h1v[k], w2[k * H2_ + n], sa);
            sb = fmaf(h1v[k], w2[k * H2_ + jbi], sb);
        }
        float hva = tanhf(sa), hvb = tanhf(sb);
        float on = b3[n];
        int base_lane = h << 5;
#pragma unroll
        for (int j2 = 0; j2 < 32; ++j2)
            on = fmaf(__shfl(hva, base_lane + j2), w3[j2 * NMAX_ + n], on);
#pragma unroll
        for (int j2 = 0; j2 < 6; ++j2)
            on = fmaf(__shfl(hvb, base_lane + j2), w3[(32 + j2) * NMAX_ + n], on);
        int aat = sorted_numbers[a];
        bool t0b = (aat & 1) != 0, t1b = (aat & 2) != 0;
        float basev = t1b ? (t0b ? spv[3] : spv[2]) : (t0b ? spv[1] : spv[0]);
        csn2[(size_t)g * NMAX_ + n] = basev + on;
    }
}

extern "C" void kernel_launch(void* const* d_in, const int* in_sizes, int n_in,
                              void* d_out, int out_size, void* d_ws, size_t ws_size,
                              hipStream_t stream) {
    const float* disp = (const float*)d_in[0];
    const float* alpha = (const float*)d_in[1];
    const float* rsp = (const float*)d_in[2];
    const float* spp = (const float*)d_in[3];
    const float* op = (const float*)d_in[4];
    const float* w1 = (const float*)d_in[5];
    const float* b1 = (const float*)d_in[6];
    const float* w2 = (const float*)d_in[7];
    const float* b2 = (const float*)d_in[8];
    const float* w3 = (const float*)d_in[9];
    const float* b3 = (const float*)d_in[10];
    const int* iidx = (const int*)d_in[11];
    const int* jidx = (const int*)d_in[12];
    const int* sn = (const int*)d_in[13];
    float* out = (float*)d_out;

    int nthr = B_ * NM_;
    int nwaves = (B_ * NA_) / 2;
    int nblocks = (nwaves + 3) / 4;

    if (ws_size >= WS_NEED) {
        float* csn2 = (float*)((char*)d_ws + CSN_OFF);
        __half* R = (__half*)((char*)d_ws + R_OFF);
        int* starts = (int*)((char*)d_ws + ST_OFF);

        starts_kernel<<<(nthr + 255) / 256, 256, 0, stream>>>(iidx, starts);
        int pblocks = (B_ * NM_ / PPT_) * 32 / 256;   // 9375
        prep0_kernel<<<pblocks, 256, 0, stream>>>(disp, alpha, rsp, jidx, sn, R);
        pass_kernel<0><<<nblocks, 256, 0, stream>>>(R, disp, jidx, spp, op, w1, b1,
                                                    w2, b2, w3, b3, sn, starts,
                                                    csn2, out);
        prep1_kernel<<<pblocks, 256, 0, stream>>>(jidx, csn2, R);
        pass_kernel<1><<<nblocks, 256, 0, stream>>>(R, disp, jidx, spp, op, w1, b1,
                                                    w2, b2, w3, b3, sn, starts,
                                                    csn2, out);
    } else {
        float* csn2 = (float*)d_ws;
        int* starts = (int*)((char*)d_ws + CSN_BYTES);
        starts_kernel<<<(nthr + 255) / 256, 256, 0, stream>>>(iidx, starts);
        fb_pass_kernel<0><<<nblocks, 256, 0, stream>>>(disp, alpha, rsp, spp, op,
                                                       w1, b1, w2, b2, w3, b3,
                                                       jidx, sn, starts, csn2, out);
        fb_pass_kernel<1><<<nblocks, 256, 0, stream>>>(disp, alpha, rsp, spp, op,
                                                       w1, b1, w2, b2, w3, b3,
                                                       jidx, sn, starts, csn2, out);
    }
}